// Round 17
// baseline (69.677 us; speedup 1.0000x reference)
//
#include <hip/hip_runtime.h>
#include <hip/hip_bf16.h>

#define NB 4
#define NN 2048
#define NF 256
#define LOG2E 1.4426950408889634f

using bf16x8 = __attribute__((ext_vector_type(8))) short;
using f32x4  = __attribute__((ext_vector_type(4))) float;
using f32x16 = __attribute__((ext_vector_type(16))) float;

__device__ __forceinline__ short f2bf(float f) {
    unsigned u = __float_as_uint(f);
    u += 0x7fffu + ((u >> 16) & 1u);   // RNE, finite inputs only
    return (short)(u >> 16);
}
__device__ __forceinline__ unsigned enc_ord(float f) {
    unsigned u = __float_as_uint(f);
    return (u & 0x80000000u) ? ~u : (u | 0x80000000u);
}
__device__ __forceinline__ float dec_ord(unsigned u) {
    unsigned i = (u & 0x80000000u) ? (u & 0x7fffffffu) : ~u;
    return __uint_as_float(i);
}
__device__ __forceinline__ void gll16(const void* g, void* l) {
    __builtin_amdgcn_global_load_lds(
        (const __attribute__((address_space(1))) unsigned int*)g,
        (__attribute__((address_space(3))) unsigned int*)l, 16, 0, 0);
}

// ---- prep: W->W^T bf16, maxfd init (tiny; must precede work2's h blocks) ----
__global__ __launch_bounds__(256) void prep_kernel(
    const float* __restrict__ W, short* __restrict__ WT, unsigned* __restrict__ maxfd)
{
    const int blk = blockIdx.x, tid = threadIdx.x;
    if (blk < (NF*NF)/256) {
        int t = blk*256 + tid;
        WT[t] = f2bf(W[(t & 255)*NF + (t >> 8)]);   // WT[g][f] = W[f][g]
    } else if (tid < NB) {
        maxfd[tid] = 0u;
    }
}

// ---- work2: blocks [0,512) = h GEMM (starts first, rides under pack's HBM
//      stream); blocks [512,4608) = adj->bitmask pack (64 B/thread) ----
__global__ __launch_bounds__(256,4) void work2_kernel(
    const int* __restrict__ adj, unsigned short* __restrict__ adjB16,
    const float* __restrict__ x, const short* __restrict__ WT, const float* __restrict__ a,
    short* __restrict__ hT, float* __restrict__ fs2, float* __restrict__ fd2,
    unsigned* __restrict__ maxfd)
{
    if (blockIdx.x >= 512) {                // pack: 1M threads x 16 ints
        const int g = (blockIdx.x - 512)*256 + threadIdx.x;
        const int4* p = (const int4*)(adj + (size_t)g*16);
        int4 v0 = p[0], v1 = p[1], v2 = p[2], v3 = p[3];
        unsigned m = 0;
        m |= (v0.x>0)<<0;  m |= (v0.y>0)<<1;  m |= (v0.z>0)<<2;  m |= (v0.w>0)<<3;
        m |= (v1.x>0)<<4;  m |= (v1.y>0)<<5;  m |= (v1.z>0)<<6;  m |= (v1.w>0)<<7;
        m |= (v2.x>0)<<8;  m |= (v2.y>0)<<9;  m |= (v2.z>0)<<10; m |= (v2.w>0)<<11;
        m |= (v3.x>0)<<12; m |= (v3.y>0)<<13; m |= (v3.z>0)<<14; m |= (v3.w>0)<<15;
        adjB16[g] = (unsigned short)m;
        return;
    }
    // ---- h = x@W (bf16 MFMA, K-pipelined) ----
    __shared__ float fs_l[16], fd_l[16];
    const int hb = blockIdx.x;
    const int w  = threadIdx.x >> 6;
    const int l  = threadIdx.x & 63;
    const int lr = l & 15, lg = l >> 4;
    const int b  = hb >> 7;
    const int ib = (hb & 127) * 16;

    if (threadIdx.x < 16) { fs_l[threadIdx.x] = 0.f; fd_l[threadIdx.x] = 0.f; }
    __syncthreads();

    f32x4 acc[4];
    #pragma unroll
    for (int t = 0; t < 4; t++) acc[t] = (f32x4){0.f,0.f,0.f,0.f};

    const float* xrow = x + (size_t)(b*NN + ib + lr) * NF + 8*lg;
    const short* wtp  = WT + (size_t)(w*64 + lr) * NF + 8*lg;

    float4 xa[2][2]; bf16x8 bfr[2][4];
    xa[0][0] = *(const float4*)(xrow);
    xa[0][1] = *(const float4*)(xrow + 4);
    #pragma unroll
    for (int nt = 0; nt < 4; nt++) bfr[0][nt] = *(const bf16x8*)(wtp + nt*16*NF);

    #pragma unroll
    for (int ks = 0; ks < 8; ks++) {
        const int cur = ks & 1;
        if (ks < 7) {
            const int nxt = cur ^ 1;
            xa[nxt][0] = *(const float4*)(xrow + (ks+1)*32);
            xa[nxt][1] = *(const float4*)(xrow + (ks+1)*32 + 4);
            #pragma unroll
            for (int nt = 0; nt < 4; nt++)
                bfr[nxt][nt] = *(const bf16x8*)(wtp + nt*16*NF + (ks+1)*32);
        }
        bf16x8 af;
        af[0]=f2bf(xa[cur][0].x); af[1]=f2bf(xa[cur][0].y);
        af[2]=f2bf(xa[cur][0].z); af[3]=f2bf(xa[cur][0].w);
        af[4]=f2bf(xa[cur][1].x); af[5]=f2bf(xa[cur][1].y);
        af[6]=f2bf(xa[cur][1].z); af[7]=f2bf(xa[cur][1].w);
        #pragma unroll
        for (int nt = 0; nt < 4; nt++)
            acc[nt] = __builtin_amdgcn_mfma_f32_16x16x32_bf16(af, bfr[cur][nt], acc[nt], 0, 0, 0);
    }

    float fsv[4] = {0,0,0,0}, fdv[4] = {0,0,0,0};
    #pragma unroll
    for (int nt = 0; nt < 4; nt++) {
        int g = w*64 + nt*16 + lr;
        float as = a[g], ad = a[NF + g];
        short4 hv;
        hv.x = f2bf(acc[nt][0]); hv.y = f2bf(acc[nt][1]);
        hv.z = f2bf(acc[nt][2]); hv.w = f2bf(acc[nt][3]);
        *(short4*)(hT + ((size_t)(b*NF + g))*NN + ib + lg*4) = hv;
        #pragma unroll
        for (int r = 0; r < 4; r++) { fsv[r] += acc[nt][r]*as; fdv[r] += acc[nt][r]*ad; }
    }
    #pragma unroll
    for (int mask = 1; mask < 16; mask <<= 1) {
        #pragma unroll
        for (int r = 0; r < 4; r++) {
            fsv[r] += __shfl_xor(fsv[r], mask);
            fdv[r] += __shfl_xor(fdv[r], mask);
        }
    }
    if (lr == 0) {
        #pragma unroll
        for (int r = 0; r < 4; r++) {
            atomicAdd(&fs_l[lg*4 + r], fsv[r]);
            atomicAdd(&fd_l[lg*4 + r], fdv[r]);
        }
    }
    __syncthreads();
    if (threadIdx.x < 16) {
        float fsu = fs_l[threadIdx.x] * LOG2E;
        float fdu = fd_l[threadIdx.x] * LOG2E;
        fs2[b*NN + ib + threadIdx.x] = fsu;
        fd2[b*NN + ib + threadIdx.x] = fdu;
        float wm = fdu;
        #pragma unroll
        for (int m = 1; m < 16; m <<= 1) wm = fmaxf(wm, __shfl_xor(wm, m));
        if (threadIdx.x == 0) atomicMax(maxfd + b, enc_ord(wm));
    }
}

// ---- fused: masked softmax + att@h + elu — 32x32x16 MFMA variant ----
// grid 512 = 4b x 64 itile(32 rows) x 2 fh(128 f); 512 thr = 8 waves = 8 kt
// (16-j slice each of BK=128). Each wave: ALL 32 rows x 128 f (4 ftiles of 32)
// -> each (i,j) exp computed ONCE per block, reused across 4 ftiles; block
// reads the 32KB B-tile exactly once (was 2x with 16x16). STAGE (4 gll) /
// LOADP (3 loads) / FENCE3 / 2x32KB slots identical to R14 (61.2us best).
// A: row=lane&31, k=8*(lane>>5)+e; C/D: col=lane&31, row=(reg&3)+8(reg>>2)+4h.
__global__ __launch_bounds__(512,4) void gat_fused(
    const short* __restrict__ hT, const unsigned char* __restrict__ adjB,
    const float* __restrict__ fs2, const float* __restrict__ fd2,
    const unsigned* __restrict__ maxfd, float* __restrict__ out)
{
    __shared__ __align__(16) char smem[66560];   // 2x32KB staging; epi: 4x16KB red + 1KB ls

    const int tid = threadIdx.x;
    const int kt = tid >> 6, l = tid & 63, fr = l & 31, h = l >> 5;
    const int blk = blockIdx.x;
    const int b = blk >> 7, rest = blk & 127;
    const int itile = rest >> 1, fh = rest & 1;
    const int i0 = itile * 32, f0 = fh * 128;

    const short* hTb = hT + ((size_t)b * NF + f0) * NN;

    // staging sources: 4 chunks/thread (2048 chunks = 32KB), inverse-XOR swizzle
    const short* sbp[4];
    #pragma unroll
    for (int i = 0; i < 4; ++i) {
        int s = tid + 512*i;
        int r = s >> 4, pc = s & 15;
        int c = pc ^ (r & 15);
        sbp[i] = hTb + (size_t)r * NN + c*8;
    }

    // this thread's P row: i0 + fr, log2-scaled constants
    const float mx2 = dec_ord(maxfd[b]);
    const int gi = b*NN + i0 + fr;
    const float fsv_ = fs2[gi];
    const float M = fmaxf(fsv_ + mx2, 0.f);
    const float fsM = fsv_ - M, nM = -M;

    const unsigned char* ar = adjB + (size_t)gi * (NN/8) + kt*2 + h;
    const float* fdp = fd2 + b*NN + kt*16 + h*8;

    // B-frag ds_read base: row fr (within ftile), chunk (kt*2+h) XOR-swizzled
    const int boff = fr*256 + (((kt*2 + h) ^ (fr & 15)) << 4);   // + ft*8192

    f32x16 acc[4] = {};
    float lsum = 0.f;

    auto STAGE = [&](int t, int slot) {          // 4 gll/thread, 32KB tile
        char* dst = smem + slot * 32768;
        #pragma unroll
        for (int i = 0; i < 4; ++i)
            gll16(sbp[i] + t*128, dst + (tid + 512*i)*16);
    };
    auto LOADP = [&](int t, unsigned& m8, f32x4& fa, f32x4& fb) {
        m8 = ar[t*16];
        fa = *(const f32x4*)(fdp + (t << 7));
        fb = *(const f32x4*)(fdp + (t << 7) + 4);
    };
    auto BODY = [&](int slot, unsigned m8, const f32x4& fa, const f32x4& fb) {
        const char* sb = smem + slot * 32768;
        bf16x8 B[4];
        #pragma unroll
        for (int ft = 0; ft < 4; ++ft)
            B[ft] = *(const bf16x8*)(sb + boff + ft*8192);
        const float fdv[8] = {fa[0],fa[1],fa[2],fa[3],fb[0],fb[1],fb[2],fb[3]};
        float p[8];
        #pragma unroll
        for (int e = 0; e < 8; ++e) {
            float v = __builtin_amdgcn_exp2f(fmaxf(fsM + fdv[e], nM));
            v = (m8 & (1u << e)) ? v : 0.f;
            lsum += v;
            p[e] = v;
        }
        union { bf16x8 v; unsigned u[4]; } au;
        #pragma unroll
        for (int d = 0; d < 4; ++d)
            asm("v_cvt_pk_bf16_f32 %0, %1, %2" : "=v"(au.u[d]) : "v"(p[2*d]), "v"(p[2*d+1]));
        #pragma unroll
        for (int ft = 0; ft < 4; ++ft)
            acc[ft] = __builtin_amdgcn_mfma_f32_32x32x16_bf16(au.v, B[ft], acc[ft], 0, 0, 0);
    };
    #define FENCE3 do { __builtin_amdgcn_sched_barrier(0); \
        asm volatile("s_waitcnt vmcnt(3)" ::: "memory"); \
        __builtin_amdgcn_s_barrier(); \
        __builtin_amdgcn_sched_barrier(0); } while (0)
    #define FENCE0 do { __builtin_amdgcn_sched_barrier(0); \
        asm volatile("s_waitcnt vmcnt(0)" ::: "memory"); \
        __builtin_amdgcn_s_barrier(); \
        __builtin_amdgcn_sched_barrier(0); } while (0)

    unsigned mA, mB;
    f32x4 fAa, fAb, fBa, fBb;

    // prologue: S0 + P0 + P1; wait S0+P0 (leave P1's 3 in flight)
    STAGE(0, 0);
    LOADP(0, mA, fAa, fAb);
    LOADP(1, mB, fBa, fBb);
    FENCE3;

    for (int t2 = 0; t2 < 16; t2 += 2) {
        // even step t2 (set A, slot 0)
        STAGE(t2 + 1, 1);
        BODY(0, mA, fAa, fAb);
        if (t2 + 2 < 16) {
            LOADP(t2 + 2, mA, fAa, fAb);
            FENCE3;                          // waits S(t2+1)+P(t2+1); leaves P(t2+2)
        } else {
            FENCE0;                          // tail: drain STAGE(15)
        }
        // odd step t2+1 (set B, slot 1)
        if (t2 + 2 < 16) STAGE(t2 + 2, 0);
        BODY(1, mB, fBa, fBb);
        if (t2 + 3 < 16) {
            LOADP(t2 + 3, mB, fBa, fBb);
            FENCE3;                          // waits S(t2+2)+P(t2+2); leaves P(t2+3)
        }
    }

    // rowsum: lanes l and l+32 share row fr -> full 16-j slice sum
    lsum += __shfl_xor(lsum, 32);
    __syncthreads();                         // loop done; LDS reused for reduction

    // ---- epilogue: 8-way kt tree (4 bufs) + rowsums ls[32][8] + elu + store ----
    float* ls = (float*)(smem + 65536);      // [32][8]
    if (h == 0) ls[fr*8 + kt] = lsum;

    auto redbuf = [&](int q) { return (float*)(smem + q*16384); };  // [32][128]
    auto STORE = [&](float* dst) {
        #pragma unroll
        for (int ft = 0; ft < 4; ++ft)
            #pragma unroll
            for (int reg = 0; reg < 16; ++reg) {
                int row = (reg & 3) + 8*(reg >> 2) + 4*h;
                dst[row*128 + ft*32 + fr] = acc[ft][reg];
            }
    };
    auto ADD = [&](const float* src) {
        #pragma unroll
        for (int ft = 0; ft < 4; ++ft)
            #pragma unroll
            for (int reg = 0; reg < 16; ++reg) {
                int row = (reg & 3) + 8*(reg >> 2) + 4*h;
                acc[ft][reg] += src[row*128 + ft*32 + fr];
            }
    };

    if (kt >= 4) STORE(redbuf(kt - 4));
    __syncthreads();
    if (kt < 4) ADD(redbuf(kt));
    __syncthreads();
    if (kt == 2 || kt == 3) STORE(redbuf(kt - 2));
    __syncthreads();
    if (kt < 2) ADD(redbuf(kt));
    __syncthreads();
    if (kt == 1) STORE(redbuf(0));
    __syncthreads();
    if (kt == 0) {
        ADD(redbuf(0));
        #pragma unroll
        for (int reg = 0; reg < 16; ++reg) {
            int row = (reg & 3) + 8*(reg >> 2) + 4*h;
            f32x4 s0 = *(const f32x4*)&ls[row*8];
            f32x4 s1 = *(const f32x4*)&ls[row*8 + 4];
            float tot = (s0[0]+s0[1]) + (s0[2]+s0[3]) + (s1[0]+s1[1]) + (s1[2]+s1[3]);
            float rv = tot > 0.f ? 1.f / tot : 0.f;
            #pragma unroll
            for (int ft = 0; ft < 4; ++ft) {
                float v = acc[ft][reg] * rv;
                v = v > 0.f ? v : expm1f(v);
                out[(size_t)(b*NN + i0 + row)*NF + f0 + ft*32 + fr] = v;
            }
        }
    }
    #undef FENCE3
    #undef FENCE0
}

extern "C" void kernel_launch(void* const* d_in, const int* in_sizes, int n_in,
                              void* d_out, int out_size, void* d_ws, size_t ws_size,
                              hipStream_t stream) {
    const float* x   = (const float*)d_in[0];
    const int*   adj = (const int*)d_in[1];
    const float* W   = (const float*)d_in[2];
    const float* a   = (const float*)d_in[3];
    float* out = (float*)d_out;
    char* ws = (char*)d_ws;

    short* WT       = (short*)(ws);                   // 128 KB
    short* hT       = (short*)(ws + 0x20000);         // 4 MB
    float* fs2      = (float*)(ws + 0x420000);        // 32 KB
    float* fd2      = (float*)(ws + 0x428000);        // 32 KB
    unsigned* maxfd = (unsigned*)(ws + 0x430000);     // 16 B
    unsigned short* adjB16 = (unsigned short*)(ws + 0x440000); // 2 MB

    prep_kernel<<<(NF*NF)/256 + 1, 256, 0, stream>>>(W, WT, maxfd);
    work2_kernel<<<4608, 256, 0, stream>>>(adj, adjB16, x, WT, a,
                                           hT, fs2, fd2, maxfd);
    gat_fused<<<NB*128, 512, 0, stream>>>(hT, (const unsigned char*)adjB16,
                                          fs2, fd2, maxfd, out);
}